// Round 9
// baseline (12.582 us; speedup 1.0000x reference)
//
#include <hip/hip_runtime.h>

// PCHIP F0 upsampler, fully fused: B=16, T=2048, SCALE=128.
// R9: identical to R8 except stores are plain float4 (non-NT) — A/B test of
// the nontemporal flag. Hypothesis: nt forces HBM-visible completion
// (~2.65us for 16.7MB) instead of acking at L2 (~0.5us).

#define TT 2048
#define BB 16
#define LL (TT * 128)
#define CHUNKS 32          // chunks per batch
#define PTS 8192           // points per chunk
#define MAXF 68            // max frames per chunk (64 + boundary + guards)

static constexpr double STEP = 2047.0 / 262143.0;  // jnp.linspace step, exact

__global__ __launch_bounds__(512) void pchip_fused(const float* __restrict__ f0,
                                                   float* __restrict__ out) {
    const int b   = blockIdx.x >> 5;   // batch
    const int c   = blockIdx.x & 31;   // chunk within batch
    const int tid = threadIdx.x;
    const int lane = tid & 63;
    const int wv   = tid >> 6;

    __shared__ unsigned short sxs[TT];   // compacted voiced positions
    __shared__ float          sys[TT];   // compacted voiced values
    __shared__ unsigned short scnt[TT];  // inclusive voiced count per frame
    __shared__ int            wsum[8];
    __shared__ int            s_nv;
    __shared__ float4         scoef[MAXF];

    const float* y = f0 + b * TT;

    // ---- load 4 frames/thread, per-thread voiced count ----
    float4 v4 = reinterpret_cast<const float4*>(y)[tid];
    float vv[4] = {v4.x, v4.y, v4.z, v4.w};
    const int t4 = tid * 4;
    int cnt = 0;
#pragma unroll
    for (int j = 0; j < 4; ++j) cnt += (vv[j] > 0.0f) ? 1 : 0;

    // ---- block-wide exclusive scan of voiced counts (8 waves) ----
    int incl = cnt;
#pragma unroll
    for (int off = 1; off < 64; off <<= 1) {
        int n = __shfl_up(incl, off, 64);
        if (lane >= off) incl += n;
    }
    if (lane == 63) wsum[wv] = incl;
    __syncthreads();
    int woff = 0;
    for (int w = 0; w < wv; ++w) woff += wsum[w];
    int run = woff + incl - cnt;  // exclusive prefix for this thread

    // ---- scatter voiced (pos,val); inclusive count per frame ----
#pragma unroll
    for (int j = 0; j < 4; ++j) {
        if (vv[j] > 0.0f) {
            sxs[run] = (unsigned short)(t4 + j);
            sys[run] = vv[j];
            ++run;
        }
        scnt[t4 + j] = (unsigned short)run;
    }
    if (tid == 511) s_nv = run;
    __syncthreads();

    // ---- frame range for this chunk (+1 guard frame each side) ----
    const int i_base = c * PTS;  // point index within batch
    const int tf_lo  = (int)((double)i_base * STEP);
    const int tf_hi  = (int)((double)(i_base + PTS - 1) * STEP);
    const int tlo2   = max(tf_lo - 1, 0);
    const int thi2   = min(tf_hi + 1, TT - 1);
    const int nf     = thi2 - tlo2 + 1;   // <= 67

    const int nv = s_nv;

    // ---- frame owners: one lane per frame, O(1) lookups ----
    if (tid < nf) {
        const int t = tlo2 + tid;
        float4 cf = make_float4(0.f, 0.f, 0.f, 0.f);
        if (nv >= 2) {
            int seg = min(max((int)scnt[t] - 1, 0), nv - 2);

            int p1 = sxs[seg];
            int p2 = sxs[seg + 1];
            float y1v = sys[seg], y2v = sys[seg + 1];
            float h    = (float)(p2 - p1);
            float winv = 1.0f / h;

            // derivative at knot `seg`
            float dsg;
            if (nv == 2) {
                dsg = (y2v - y1v) * winv;
            } else if (seg == 0) {
                int p3 = sxs[2];
                float h0 = (float)(p2 - p1), h1 = (float)(p3 - p2);
                float del0 = (y2v - y1v) / h0;
                float del1 = (sys[2] - y2v) / h1;
                float d0 = ((2.0f * h0 + h1) * del0 - h0 * del1) / (h0 + h1);
                if (d0 * del0 <= 0.0f) d0 = 0.0f;
                else if (del0 * del1 < 0.0f && fabsf(d0) > 3.0f * fabsf(del0)) d0 = 3.0f * del0;
                dsg = d0;
            } else {
                int p0 = sxs[seg - 1];
                float hkm1 = (float)(p1 - p0), hk = (float)(p2 - p1);
                float dkm1 = (y1v - sys[seg - 1]) / hkm1;
                float dkk  = (y2v - y1v) / hk;
                if (dkm1 * dkk > 0.0f) {
                    float w1 = 2.0f * hk + hkm1, w2 = hk + 2.0f * hkm1;
                    dsg = (w1 + w2) / (w1 / dkm1 + w2 / dkk);
                } else dsg = 0.0f;
            }

            // derivative at knot `seg+1`
            float dsg1;
            if (nv == 2) {
                dsg1 = (y2v - y1v) * winv;
            } else if (seg + 1 == nv - 1) {
                int p0 = sxs[seg - 1];                       // nv-3
                float hm1 = (float)(p2 - p1), hm2 = (float)(p1 - p0);
                float dm1 = (y2v - y1v) / hm1;
                float dm2 = (y1v - sys[seg - 1]) / hm2;
                float dn = ((2.0f * hm1 + hm2) * dm1 - hm1 * dm2) / (hm1 + hm2);
                if (dn * dm1 <= 0.0f) dn = 0.0f;
                else if (dm1 * dm2 < 0.0f && fabsf(dn) > 3.0f * fabsf(dm1)) dn = 3.0f * dm1;
                dsg1 = dn;
            } else {
                int p3 = sxs[seg + 2];
                float hkm1 = (float)(p2 - p1), hk = (float)(p3 - p2);
                float dkm1 = (y2v - y1v) / hkm1;
                float dkk  = (sys[seg + 2] - y2v) / hk;
                if (dkm1 * dkk > 0.0f) {
                    float w1 = 2.0f * hk + hkm1, w2 = hk + 2.0f * hkm1;
                    dsg1 = (w1 + w2) / (w1 / dkm1 + w2 / dkk);
                } else dsg1 = 0.0f;
            }

            // recentered cubic coeffs at frame t (u in [0,1))
            float hg0 = h * dsg, hg1 = h * dsg1;
            float D  = y2v - y1v;
            float b1 = hg0;
            float b2 = 3.0f * D - 2.0f * hg0 - hg1;
            float b3 = hg0 + hg1 - 2.0f * D;
            float t0 = ((float)t - (float)p1) * winv;
            float a0 = ((b3 * t0 + b2) * t0 + b1) * t0 + y1v;
            float a1 = winv * ((3.0f * b3 * t0 + 2.0f * b2) * t0 + b1);
            float a2 = winv * winv * (b2 + 3.0f * b3 * t0);
            float a3 = winv * winv * winv * b3;

            // voiced flags from scnt diffs
            unsigned k0 = ((int)scnt[t] > (t > 0 ? (int)scnt[t - 1] : 0)) ? 1u : 0u;
            int t1 = min(t + 1, TT - 1);
            unsigned k1 = ((int)scnt[t1] > (t1 > 0 ? (int)scnt[t1 - 1] : 0)) ? 1u : 0u;
            unsigned ua3 = (__float_as_uint(a3) & ~3u) | k0 | (k1 << 1);
            cf = make_float4(a0, a1, a2, __uint_as_float(ua3));
        }
        scoef[tid] = cf;
    }
    __syncthreads();

    // ---- evaluate 16 points/thread, conditional coef reload, plain stores ----
    float4* og = reinterpret_cast<float4*>(out + (size_t)b * LL + i_base);
#pragma unroll
    for (int g = 0; g < 4; ++g) {
        const int ii = g * 2048 + tid * 4;   // local point index (4 consecutive)
        const int ib = i_base + ii;
        float r[4];
        float4 a = make_float4(0.f, 0.f, 0.f, 0.f);
        int tf_cur = -1;
#pragma unroll
        for (int j = 0; j < 4; ++j) {
            double ux = (double)(ib + j) * STEP;  // exact reference up_x
            float uxf = (float)ux;                // reference's f32 cast
            int tf = (int)uxf;                    // floor (uxf >= 0)
            if (tf != tf_cur) {                   // at most once per 4 points
                a = scoef[tf - tlo2];
                tf_cur = tf;
            }
            float u = uxf - (float)tf;            // exact subtraction
            unsigned kc = __float_as_uint(a.w) & 3u;
            float up = fmaf(u, fmaf(u, fmaf(u, a.w, a.z), a.y), a.x);
            up = fmaxf(up, 0.0f);
            int back = (int)rintf(uxf);           // round-half-even
            unsigned kb = (kc >> (back - tf)) & 1u;
            r[j] = kb ? up : 0.0f;
        }
        og[ii >> 2] = make_float4(r[0], r[1], r[2], r[3]);
    }
}

extern "C" void kernel_launch(void* const* d_in, const int* in_sizes, int n_in,
                              void* d_out, int out_size, void* d_ws, size_t ws_size,
                              hipStream_t stream) {
    const float* f0 = (const float*)d_in[0];
    float* out = (float*)d_out;
    pchip_fused<<<BB * CHUNKS, 512, 0, stream>>>(f0, out);
}

// Round 10
// 11.945 us; speedup vs baseline: 1.0533x; 1.0533x over previous
//
#include <hip/hip_runtime.h>

// PCHIP F0 upsampler, fully fused: B=16, T=2048, SCALE=128.
// R10: R8 structure (O(1) owner lookups, NT stores — A/B-confirmed better
// than plain in R9) with 1024-thread blocks / 16 chunks per batch:
// scatter chain 2-deep, 256 total blocks (1/CU), half the redundant scans.

#define TT 2048
#define BB 16
#define LL (TT * 128)
#define CHUNKS 16          // chunks per batch
#define PTS 16384          // points per chunk
#define MAXF 132           // max frames per chunk (128 + boundary + guards)

typedef float vf4 __attribute__((ext_vector_type(4)));

static constexpr double STEP = 2047.0 / 262143.0;  // jnp.linspace step, exact

__global__ __launch_bounds__(1024) void pchip_fused(const float* __restrict__ f0,
                                                    float* __restrict__ out) {
    const int b   = blockIdx.x >> 4;   // batch
    const int c   = blockIdx.x & 15;   // chunk within batch
    const int tid = threadIdx.x;
    const int lane = tid & 63;
    const int wv   = tid >> 6;

    __shared__ unsigned short sxs[TT];   // compacted voiced positions
    __shared__ float          sys[TT];   // compacted voiced values
    __shared__ unsigned short scnt[TT];  // inclusive voiced count per frame
    __shared__ int            wsum[16];
    __shared__ int            s_nv;
    __shared__ float4         scoef[MAXF];

    const float* y = f0 + b * TT;

    // ---- load 2 frames/thread, per-thread voiced count ----
    float2 v2 = reinterpret_cast<const float2*>(y)[tid];
    float vv[2] = {v2.x, v2.y};
    const int t2 = tid * 2;
    int cnt = (vv[0] > 0.0f ? 1 : 0) + (vv[1] > 0.0f ? 1 : 0);

    // ---- block-wide exclusive scan of voiced counts (16 waves) ----
    int incl = cnt;
#pragma unroll
    for (int off = 1; off < 64; off <<= 1) {
        int n = __shfl_up(incl, off, 64);
        if (lane >= off) incl += n;
    }
    if (lane == 63) wsum[wv] = incl;
    __syncthreads();
    int woff = 0;
    for (int w = 0; w < wv; ++w) woff += wsum[w];
    int run = woff + incl - cnt;  // exclusive prefix for this thread

    // ---- scatter voiced (pos,val); inclusive count per frame (2-deep) ----
#pragma unroll
    for (int j = 0; j < 2; ++j) {
        if (vv[j] > 0.0f) {
            sxs[run] = (unsigned short)(t2 + j);
            sys[run] = vv[j];
            ++run;
        }
        scnt[t2 + j] = (unsigned short)run;
    }
    if (tid == 1023) s_nv = run;
    __syncthreads();

    // ---- frame range for this chunk (+1 guard frame each side) ----
    const int i_base = c * PTS;  // point index within batch
    const int tf_lo  = (int)((double)i_base * STEP);
    const int tf_hi  = (int)((double)(i_base + PTS - 1) * STEP);
    const int tlo2   = max(tf_lo - 1, 0);
    const int thi2   = min(tf_hi + 1, TT - 1);
    const int nf     = thi2 - tlo2 + 1;   // <= 131

    const int nv = s_nv;

    // ---- frame owners: one lane per frame, O(1) lookups ----
    if (tid < nf) {
        const int t = tlo2 + tid;
        float4 cf = make_float4(0.f, 0.f, 0.f, 0.f);
        if (nv >= 2) {
            int seg = min(max((int)scnt[t] - 1, 0), nv - 2);

            int p1 = sxs[seg];
            int p2 = sxs[seg + 1];
            float y1v = sys[seg], y2v = sys[seg + 1];
            float h    = (float)(p2 - p1);
            float winv = 1.0f / h;

            // derivative at knot `seg`
            float dsg;
            if (nv == 2) {
                dsg = (y2v - y1v) * winv;
            } else if (seg == 0) {
                int p3 = sxs[2];
                float h0 = (float)(p2 - p1), h1 = (float)(p3 - p2);
                float del0 = (y2v - y1v) / h0;
                float del1 = (sys[2] - y2v) / h1;
                float d0 = ((2.0f * h0 + h1) * del0 - h0 * del1) / (h0 + h1);
                if (d0 * del0 <= 0.0f) d0 = 0.0f;
                else if (del0 * del1 < 0.0f && fabsf(d0) > 3.0f * fabsf(del0)) d0 = 3.0f * del0;
                dsg = d0;
            } else {
                int p0 = sxs[seg - 1];
                float hkm1 = (float)(p1 - p0), hk = (float)(p2 - p1);
                float dkm1 = (y1v - sys[seg - 1]) / hkm1;
                float dkk  = (y2v - y1v) / hk;
                if (dkm1 * dkk > 0.0f) {
                    float w1 = 2.0f * hk + hkm1, w2 = hk + 2.0f * hkm1;
                    dsg = (w1 + w2) / (w1 / dkm1 + w2 / dkk);
                } else dsg = 0.0f;
            }

            // derivative at knot `seg+1`
            float dsg1;
            if (nv == 2) {
                dsg1 = (y2v - y1v) * winv;
            } else if (seg + 1 == nv - 1) {
                int p0 = sxs[seg - 1];                       // nv-3
                float hm1 = (float)(p2 - p1), hm2 = (float)(p1 - p0);
                float dm1 = (y2v - y1v) / hm1;
                float dm2 = (y1v - sys[seg - 1]) / hm2;
                float dn = ((2.0f * hm1 + hm2) * dm1 - hm1 * dm2) / (hm1 + hm2);
                if (dn * dm1 <= 0.0f) dn = 0.0f;
                else if (dm1 * dm2 < 0.0f && fabsf(dn) > 3.0f * fabsf(dm1)) dn = 3.0f * dm1;
                dsg1 = dn;
            } else {
                int p3 = sxs[seg + 2];
                float hkm1 = (float)(p2 - p1), hk = (float)(p3 - p2);
                float dkm1 = (y2v - y1v) / hkm1;
                float dkk  = (sys[seg + 2] - y2v) / hk;
                if (dkm1 * dkk > 0.0f) {
                    float w1 = 2.0f * hk + hkm1, w2 = hk + 2.0f * hkm1;
                    dsg1 = (w1 + w2) / (w1 / dkm1 + w2 / dkk);
                } else dsg1 = 0.0f;
            }

            // recentered cubic coeffs at frame t (u in [0,1))
            float hg0 = h * dsg, hg1 = h * dsg1;
            float D  = y2v - y1v;
            float b1 = hg0;
            float b2 = 3.0f * D - 2.0f * hg0 - hg1;
            float b3 = hg0 + hg1 - 2.0f * D;
            float t0 = ((float)t - (float)p1) * winv;
            float a0 = ((b3 * t0 + b2) * t0 + b1) * t0 + y1v;
            float a1 = winv * ((3.0f * b3 * t0 + 2.0f * b2) * t0 + b1);
            float a2 = winv * winv * (b2 + 3.0f * b3 * t0);
            float a3 = winv * winv * winv * b3;

            // voiced flags from scnt diffs
            unsigned k0 = ((int)scnt[t] > (t > 0 ? (int)scnt[t - 1] : 0)) ? 1u : 0u;
            int t1 = min(t + 1, TT - 1);
            unsigned k1 = ((int)scnt[t1] > (t1 > 0 ? (int)scnt[t1 - 1] : 0)) ? 1u : 0u;
            unsigned ua3 = (__float_as_uint(a3) & ~3u) | k0 | (k1 << 1);
            cf = make_float4(a0, a1, a2, __uint_as_float(ua3));
        }
        scoef[tid] = cf;
    }
    __syncthreads();

    // ---- evaluate 16 points/thread, conditional coef reload, NT stores ----
    vf4* og = reinterpret_cast<vf4*>(out + (size_t)b * LL + i_base);
#pragma unroll
    for (int g = 0; g < 4; ++g) {
        const int ii = g * 4096 + tid * 4;   // local point index (4 consecutive)
        const int ib = i_base + ii;
        float r[4];
        float4 a = make_float4(0.f, 0.f, 0.f, 0.f);
        int tf_cur = -1;
#pragma unroll
        for (int j = 0; j < 4; ++j) {
            double ux = (double)(ib + j) * STEP;  // exact reference up_x
            float uxf = (float)ux;                // reference's f32 cast
            int tf = (int)uxf;                    // floor (uxf >= 0)
            if (tf != tf_cur) {                   // at most once per 4 points
                a = scoef[tf - tlo2];
                tf_cur = tf;
            }
            float u = uxf - (float)tf;            // exact subtraction
            unsigned kc = __float_as_uint(a.w) & 3u;
            float up = fmaf(u, fmaf(u, fmaf(u, a.w, a.z), a.y), a.x);
            up = fmaxf(up, 0.0f);
            int back = (int)rintf(uxf);           // round-half-even
            unsigned kb = (kc >> (back - tf)) & 1u;
            r[j] = kb ? up : 0.0f;
        }
        vf4 rv = {r[0], r[1], r[2], r[3]};
        __builtin_nontemporal_store(rv, &og[ii >> 2]);
    }
}

extern "C" void kernel_launch(void* const* d_in, const int* in_sizes, int n_in,
                              void* d_out, int out_size, void* d_ws, size_t ws_size,
                              hipStream_t stream) {
    const float* f0 = (const float*)d_in[0];
    float* out = (float*)d_out;
    pchip_fused<<<BB * CHUNKS, 1024, 0, stream>>>(f0, out);
}

// Round 11
// 11.091 us; speedup vs baseline: 1.1344x; 1.0770x over previous
//
#include <hip/hip_runtime.h>

// PCHIP F0 upsampler, fully fused: B=16, T=2048, SCALE=128.
// FINAL (R8 config, measured best 11.1us): one kernel, 512 blocks x 512
// threads; per-block in-LDS voiced compaction (prefix scan -> O(1) owner
// lookups), f64 only for the bit-exact up_x cast, frame-local cubic coeffs
// with packed keep-code, conditional coef reload, nontemporal stores
// (A/B-confirmed faster than plain: write-once output streams to HBM
// without L2 allocation).

#define TT 2048
#define BB 16
#define LL (TT * 128)
#define CHUNKS 32          // chunks per batch
#define PTS 8192           // points per chunk
#define MAXF 68            // max frames per chunk (64 + boundary + guards)

typedef float vf4 __attribute__((ext_vector_type(4)));

static constexpr double STEP = 2047.0 / 262143.0;  // jnp.linspace step, exact

__global__ __launch_bounds__(512) void pchip_fused(const float* __restrict__ f0,
                                                   float* __restrict__ out) {
    const int b   = blockIdx.x >> 5;   // batch
    const int c   = blockIdx.x & 31;   // chunk within batch
    const int tid = threadIdx.x;
    const int lane = tid & 63;
    const int wv   = tid >> 6;

    __shared__ unsigned short sxs[TT];   // compacted voiced positions
    __shared__ float          sys[TT];   // compacted voiced values
    __shared__ unsigned short scnt[TT];  // inclusive voiced count per frame
    __shared__ int            wsum[8];
    __shared__ int            s_nv;
    __shared__ float4         scoef[MAXF];

    const float* y = f0 + b * TT;

    // ---- load 4 frames/thread, per-thread voiced count ----
    float4 v4 = reinterpret_cast<const float4*>(y)[tid];
    float vv[4] = {v4.x, v4.y, v4.z, v4.w};
    const int t4 = tid * 4;
    int cnt = 0;
#pragma unroll
    for (int j = 0; j < 4; ++j) cnt += (vv[j] > 0.0f) ? 1 : 0;

    // ---- block-wide exclusive scan of voiced counts (8 waves) ----
    int incl = cnt;
#pragma unroll
    for (int off = 1; off < 64; off <<= 1) {
        int n = __shfl_up(incl, off, 64);
        if (lane >= off) incl += n;
    }
    if (lane == 63) wsum[wv] = incl;
    __syncthreads();
    int woff = 0;
    for (int w = 0; w < wv; ++w) woff += wsum[w];
    int run = woff + incl - cnt;  // exclusive prefix for this thread

    // ---- scatter voiced (pos,val); inclusive count per frame ----
#pragma unroll
    for (int j = 0; j < 4; ++j) {
        if (vv[j] > 0.0f) {
            sxs[run] = (unsigned short)(t4 + j);
            sys[run] = vv[j];
            ++run;
        }
        scnt[t4 + j] = (unsigned short)run;
    }
    if (tid == 511) s_nv = run;
    __syncthreads();

    // ---- frame range for this chunk (+1 guard frame each side) ----
    const int i_base = c * PTS;  // point index within batch
    const int tf_lo  = (int)((double)i_base * STEP);
    const int tf_hi  = (int)((double)(i_base + PTS - 1) * STEP);
    const int tlo2   = max(tf_lo - 1, 0);
    const int thi2   = min(tf_hi + 1, TT - 1);
    const int nf     = thi2 - tlo2 + 1;   // <= 67

    const int nv = s_nv;

    // ---- frame owners: one lane per frame, O(1) lookups ----
    if (tid < nf) {
        const int t = tlo2 + tid;
        float4 cf = make_float4(0.f, 0.f, 0.f, 0.f);
        if (nv >= 2) {
            int seg = min(max((int)scnt[t] - 1, 0), nv - 2);

            int p1 = sxs[seg];
            int p2 = sxs[seg + 1];
            float y1v = sys[seg], y2v = sys[seg + 1];
            float h    = (float)(p2 - p1);
            float winv = 1.0f / h;

            // derivative at knot `seg`
            float dsg;
            if (nv == 2) {
                dsg = (y2v - y1v) * winv;
            } else if (seg == 0) {
                int p3 = sxs[2];
                float h0 = (float)(p2 - p1), h1 = (float)(p3 - p2);
                float del0 = (y2v - y1v) / h0;
                float del1 = (sys[2] - y2v) / h1;
                float d0 = ((2.0f * h0 + h1) * del0 - h0 * del1) / (h0 + h1);
                if (d0 * del0 <= 0.0f) d0 = 0.0f;
                else if (del0 * del1 < 0.0f && fabsf(d0) > 3.0f * fabsf(del0)) d0 = 3.0f * del0;
                dsg = d0;
            } else {
                int p0 = sxs[seg - 1];
                float hkm1 = (float)(p1 - p0), hk = (float)(p2 - p1);
                float dkm1 = (y1v - sys[seg - 1]) / hkm1;
                float dkk  = (y2v - y1v) / hk;
                if (dkm1 * dkk > 0.0f) {
                    float w1 = 2.0f * hk + hkm1, w2 = hk + 2.0f * hkm1;
                    dsg = (w1 + w2) / (w1 / dkm1 + w2 / dkk);
                } else dsg = 0.0f;
            }

            // derivative at knot `seg+1`
            float dsg1;
            if (nv == 2) {
                dsg1 = (y2v - y1v) * winv;
            } else if (seg + 1 == nv - 1) {
                int p0 = sxs[seg - 1];                       // nv-3
                float hm1 = (float)(p2 - p1), hm2 = (float)(p1 - p0);
                float dm1 = (y2v - y1v) / hm1;
                float dm2 = (y1v - sys[seg - 1]) / hm2;
                float dn = ((2.0f * hm1 + hm2) * dm1 - hm1 * dm2) / (hm1 + hm2);
                if (dn * dm1 <= 0.0f) dn = 0.0f;
                else if (dm1 * dm2 < 0.0f && fabsf(dn) > 3.0f * fabsf(dm1)) dn = 3.0f * dm1;
                dsg1 = dn;
            } else {
                int p3 = sxs[seg + 2];
                float hkm1 = (float)(p2 - p1), hk = (float)(p3 - p2);
                float dkm1 = (y2v - y1v) / hkm1;
                float dkk  = (sys[seg + 2] - y2v) / hk;
                if (dkm1 * dkk > 0.0f) {
                    float w1 = 2.0f * hk + hkm1, w2 = hk + 2.0f * hkm1;
                    dsg1 = (w1 + w2) / (w1 / dkm1 + w2 / dkk);
                } else dsg1 = 0.0f;
            }

            // recentered cubic coeffs at frame t (u in [0,1))
            float hg0 = h * dsg, hg1 = h * dsg1;
            float D  = y2v - y1v;
            float b1 = hg0;
            float b2 = 3.0f * D - 2.0f * hg0 - hg1;
            float b3 = hg0 + hg1 - 2.0f * D;
            float t0 = ((float)t - (float)p1) * winv;
            float a0 = ((b3 * t0 + b2) * t0 + b1) * t0 + y1v;
            float a1 = winv * ((3.0f * b3 * t0 + 2.0f * b2) * t0 + b1);
            float a2 = winv * winv * (b2 + 3.0f * b3 * t0);
            float a3 = winv * winv * winv * b3;

            // voiced flags from scnt diffs
            unsigned k0 = ((int)scnt[t] > (t > 0 ? (int)scnt[t - 1] : 0)) ? 1u : 0u;
            int t1 = min(t + 1, TT - 1);
            unsigned k1 = ((int)scnt[t1] > (t1 > 0 ? (int)scnt[t1 - 1] : 0)) ? 1u : 0u;
            unsigned ua3 = (__float_as_uint(a3) & ~3u) | k0 | (k1 << 1);
            cf = make_float4(a0, a1, a2, __uint_as_float(ua3));
        }
        scoef[tid] = cf;
    }
    __syncthreads();

    // ---- evaluate 16 points/thread, conditional coef reload, NT stores ----
    vf4* og = reinterpret_cast<vf4*>(out + (size_t)b * LL + i_base);
#pragma unroll
    for (int g = 0; g < 4; ++g) {
        const int ii = g * 2048 + tid * 4;   // local point index (4 consecutive)
        const int ib = i_base + ii;
        float r[4];
        float4 a = make_float4(0.f, 0.f, 0.f, 0.f);
        int tf_cur = -1;
#pragma unroll
        for (int j = 0; j < 4; ++j) {
            double ux = (double)(ib + j) * STEP;  // exact reference up_x
            float uxf = (float)ux;                // reference's f32 cast
            int tf = (int)uxf;                    // floor (uxf >= 0)
            if (tf != tf_cur) {                   // at most once per 4 points
                a = scoef[tf - tlo2];
                tf_cur = tf;
            }
            float u = uxf - (float)tf;            // exact subtraction
            unsigned kc = __float_as_uint(a.w) & 3u;
            float up = fmaf(u, fmaf(u, fmaf(u, a.w, a.z), a.y), a.x);
            up = fmaxf(up, 0.0f);
            int back = (int)rintf(uxf);           // round-half-even
            unsigned kb = (kc >> (back - tf)) & 1u;
            r[j] = kb ? up : 0.0f;
        }
        vf4 rv = {r[0], r[1], r[2], r[3]};
        __builtin_nontemporal_store(rv, &og[ii >> 2]);
    }
}

extern "C" void kernel_launch(void* const* d_in, const int* in_sizes, int n_in,
                              void* d_out, int out_size, void* d_ws, size_t ws_size,
                              hipStream_t stream) {
    const float* f0 = (const float*)d_in[0];
    float* out = (float*)d_out;
    pchip_fused<<<BB * CHUNKS, 512, 0, stream>>>(f0, out);
}